// Round 3
// baseline (265.213 us; speedup 1.0000x reference)
//
#include <hip/hip_runtime.h>
#include <hip/hip_bf16.h>

#define E 1024
#define DK 64
#define SEQ 4096
#define NB 4
// 0.125 * log2(e): scores arrive pre-multiplied so softmax = exp2(s) = v_exp_f32
#define KSCALE 0.18033688011112042f

typedef short bf16x8 __attribute__((ext_vector_type(8)));
typedef short bf16x4 __attribute__((ext_vector_type(4)));
typedef float f32x4 __attribute__((ext_vector_type(4)));
typedef unsigned short u16x8 __attribute__((ext_vector_type(8)));

typedef const __attribute__((address_space(1))) unsigned int* gcp;
typedef __attribute__((address_space(3))) unsigned int* lcp;

__device__ inline unsigned short f2bf(float f) {
    unsigned int u = __float_as_uint(f);
    u += 0x7fff + ((u >> 16) & 1);   // round-to-nearest-even
    return (unsigned short)(u >> 16);
}
__device__ inline unsigned int cvtpk(float a, float b) {
    union { __hip_bfloat162 h; unsigned int u; } x;
    x.h = __float22bfloat162_rn(make_float2(a, b));
    return x.u;
}
__device__ inline bf16x8 cvt8(f32x4 a, f32x4 b) {
    union { unsigned int u[4]; bf16x8 v; } x;
    x.u[0] = cvtpk(a[0], a[1]); x.u[1] = cvtpk(a[2], a[3]);
    x.u[2] = cvtpk(b[0], b[1]); x.u[3] = cvtpk(b[2], b[3]);
    return x.v;
}

// ---------------- Kernel 0: W [1024][64] fp32 -> Wt [64][1024] bf16 (LDS transpose) --------
__global__ __launch_bounds__(256) void wt_kernel(
    const float* __restrict__ Wq, const float* __restrict__ Wk, const float* __restrict__ Wv,
    unsigned short* __restrict__ wtq, unsigned short* __restrict__ wtk, unsigned short* __restrict__ wtv)
{
    const float* src; unsigned short* dst;
    if (blockIdx.y == 0)      { src = Wq; dst = wtq; }
    else if (blockIdx.y == 1) { src = Wk; dst = wtk; }
    else                      { src = Wv; dst = wtv; }
    const int tid = threadIdx.x;
    const int e0 = blockIdx.x * 64;
    __shared__ float Ws[64][65];
    #pragma unroll
    for (int i = 0; i < 4; ++i) {
        int flat = i * 256 + tid;
        int r = flat >> 4;
        int c4 = (flat & 15) << 2;
        float4 v = *reinterpret_cast<const float4*>(&src[(size_t)(e0 + r) * DK + c4]);
        Ws[c4 + 0][r] = v.x; Ws[c4 + 1][r] = v.y; Ws[c4 + 2][r] = v.z; Ws[c4 + 3][r] = v.w;
    }
    __syncthreads();
    #pragma unroll
    for (int i = 0; i < 4; ++i) {
        int flat = i * 256 + tid;
        int c = flat >> 4;
        int r4 = (flat & 15) << 2;
        ushort4 o;
        o.x = f2bf(Ws[c][r4 + 0]); o.y = f2bf(Ws[c][r4 + 1]);
        o.z = f2bf(Ws[c][r4 + 2]); o.w = f2bf(Ws[c][r4 + 3]);
        *reinterpret_cast<ushort4*>(&dst[(size_t)c * E + e0 + r4]) = o;
    }
}

// ---------------- Kernel 1: QKV projection — main loop unchanged; LDS-coalesced epilogue --
// R2 counters: MfmaUtil 4.5 / VALU 7.5 / 19% HBM -> latency+transaction bound. The V^T
// epilogue was 16 store instrs/wave of fully-scattered 2B lanes (8KB stride): ~64 serialized
// address groups each. New epilogue: stage Q/K (token-major) and V^T (d-major) tiles in LDS
// as bf16, then store coalesced 128B rows (2 dwordx4 instrs/wave for Q/K, +2 for V).
__global__ __launch_bounds__(256, 4) void proj_kernel(
    const float* __restrict__ in_q, const float* __restrict__ in_kv,
    const unsigned short* __restrict__ wtq, const unsigned short* __restrict__ wtk,
    const unsigned short* __restrict__ wtv,
    const float* __restrict__ bq, const float* __restrict__ bk, const float* __restrict__ bv,
    unsigned short* __restrict__ Qw, unsigned short* __restrict__ Kw, unsigned short* __restrict__ Vtw)
{
    const int tid = threadIdx.x;
    const int w = tid >> 6, lane = tid & 63, quad = lane >> 4, l16 = lane & 15;
    const int row0 = blockIdx.x * 64;
    const bool isQ = (blockIdx.y == 0);
    const float* Arow = (isQ ? in_q : in_kv) + (size_t)(row0 + w * 16 + l16) * E;
    const unsigned short* w0 = isQ ? wtq : wtk;

    __shared__ unsigned short W0s[2][4096];   // 16 KB
    __shared__ unsigned short W1s[2][4096];   // 16 KB
    __shared__ unsigned short Cs0[64][68];    // 8.7 KB: Q or K, [token][d]
    __shared__ unsigned short Cs1[64][68];    // 8.7 KB: V^T, [d][token]

    const int rl = lane >> 3, pp = lane & 7;

    #pragma unroll
    for (int i = 0; i < 2; ++i) {
        int g = w * 2 + i;
        int r = g * 8 + rl;
        int lc = pp ^ (r & 7);
        __builtin_amdgcn_global_load_lds((gcp)(const void*)(w0 + (size_t)r * E + lc * 8),
                                         (lcp)(void*)&W0s[0][g * 512], 16, 0, 0);
        if (!isQ)
            __builtin_amdgcn_global_load_lds((gcp)(const void*)(wtv + (size_t)r * E + lc * 8),
                                             (lcp)(void*)&W1s[0][g * 512], 16, 0, 0);
    }
    f32x4 a_cur[4];
    #pragma unroll
    for (int ks = 0; ks < 2; ++ks)
        #pragma unroll
        for (int j = 0; j < 2; ++j)
            a_cur[ks * 2 + j] = *reinterpret_cast<const f32x4*>(Arow + ks * 32 + quad * 8 + j * 4);
    __syncthreads();

    f32x4 acc0[4] = {};
    f32x4 acc1[4] = {};

    for (int kb = 0; kb < 16; ++kb) {
        const int cur = kb & 1, nxt = cur ^ 1;
        f32x4 a_nxt[4];
        if (kb < 15) {
            const int ko = (kb + 1) * 64;
            #pragma unroll
            for (int i = 0; i < 2; ++i) {
                int g = w * 2 + i;
                int r = g * 8 + rl;
                int lc = pp ^ (r & 7);
                __builtin_amdgcn_global_load_lds((gcp)(const void*)(w0 + (size_t)r * E + ko + lc * 8),
                                                 (lcp)(void*)&W0s[nxt][g * 512], 16, 0, 0);
                if (!isQ)
                    __builtin_amdgcn_global_load_lds((gcp)(const void*)(wtv + (size_t)r * E + ko + lc * 8),
                                                     (lcp)(void*)&W1s[nxt][g * 512], 16, 0, 0);
            }
            const float* an = Arow + ko;
            #pragma unroll
            for (int ks = 0; ks < 2; ++ks)
                #pragma unroll
                for (int j = 0; j < 2; ++j)
                    a_nxt[ks * 2 + j] = *reinterpret_cast<const f32x4*>(an + ks * 32 + quad * 8 + j * 4);
        }
        #pragma unroll
        for (int ks = 0; ks < 2; ++ks) {
            bf16x8 af = cvt8(a_cur[ks * 2], a_cur[ks * 2 + 1]);
            #pragma unroll
            for (int ct = 0; ct < 4; ++ct) {
                int brow = ct * 16 + l16;
                int pc = (ks * 4 + quad) ^ (brow & 7);
                bf16x8 b0 = *reinterpret_cast<const bf16x8*>(&W0s[cur][brow * 64 + pc * 8]);
                acc0[ct] = __builtin_amdgcn_mfma_f32_16x16x32_bf16(af, b0, acc0[ct], 0, 0, 0);
                if (!isQ) {
                    bf16x8 b1 = *reinterpret_cast<const bf16x8*>(&W1s[cur][brow * 64 + pc * 8]);
                    acc1[ct] = __builtin_amdgcn_mfma_f32_16x16x32_bf16(af, b1, acc1[ct], 0, 0, 0);
                }
            }
        }
        #pragma unroll
        for (int j = 0; j < 4; ++j) a_cur[j] = a_nxt[j];
        if (kb < 15) __syncthreads();
    }

    // ---- epilogue: C/D layout col=lane&15, row=quad*4+reg. Stage in LDS, store coalesced.
    const int tl0 = w * 16 + quad * 4;                     // token-local base
    #pragma unroll
    for (int ct = 0; ct < 4; ++ct) {
        int col = ct * 16 + l16;
        if (isQ) {
            float bias = bq[col];
            #pragma unroll
            for (int r = 0; r < 4; ++r)
                Cs0[tl0 + r][col] = f2bf(acc0[ct][r] + bias);
        } else {
            float biask = bk[col], biasv = bv[col];
            #pragma unroll
            for (int r = 0; r < 4; ++r) {
                Cs0[tl0 + r][col] = f2bf((acc0[ct][r] + biask) * KSCALE);
                Cs1[col][tl0 + r] = f2bf(acc1[ct][r] + biasv);
            }
        }
    }
    __syncthreads();

    // coalesced stores: wave w handles rows w*16..w*16+15, 128B per row
    const int bb = row0 >> 12, tok0 = row0 & 4095;
    #pragma unroll
    for (int jj = 0; jj < 2; ++jj) {
        int rr = w * 16 + jj * 8 + (lane >> 3);
        int c8 = (lane & 7) * 8;
        u16x8 v0 = *reinterpret_cast<const u16x8*>(&Cs0[rr][c8]);
        if (isQ) {
            *reinterpret_cast<u16x8*>(&Qw[(size_t)(row0 + rr) * DK + c8]) = v0;
        } else {
            *reinterpret_cast<u16x8*>(&Kw[(size_t)(row0 + rr) * DK + c8]) = v0;
            u16x8 v1 = *reinterpret_cast<const u16x8*>(&Cs1[rr][c8]);
            *reinterpret_cast<u16x8*>(&Vtw[((size_t)(bb * 64 + rr)) * SEQ + tok0 + c8]) = v1;
        }
    }
}

// ---------------- Kernel 2: flash attention — register-direct, barrier-free, 16 waves ----
// R0/R1/R2 jointly: time ~ linear in per-CU K/V bytes; DMA-contiguous access only -9%;
// busy ~40% (incl. ~20cyc/instr legacy 16x16x16_1k PV MFMA), rest = chain stalls that
// 2 waves/SIMD can't hide. Fix: R0's proven barrier-free register-direct body, but 1024
// threads = 16 waves = 4/SIMD at UNCHANGED per-CU bytes (same 64 q & full K/V per block).
// Wave w: key-slice (w&3)*16, tile parity w>>2 over 4 -> 16 iters of 64-key tiles, one
// tile prefetched ahead in registers. S^T C-layout feeds PV 16x16x16 B-operand directly.
__global__ __launch_bounds__(1024) void attn_kernel(
    const unsigned short* __restrict__ Qw, const unsigned short* __restrict__ Kw,
    const unsigned short* __restrict__ Vtw, float* __restrict__ out)
{
    const int tid = threadIdx.x;
    const int w = tid >> 6, lane = tid & 63, quad = lane >> 4, l16 = lane & 15;
    const int wk = w & 3, wp = w >> 2;                          // 4 slices x 4 parities
    const int b = (blockIdx.x & 7) >> 1;                        // XCD-aware: 2 MB K/V per XCD
    const int qt = ((blockIdx.x >> 3) << 1) | (blockIdx.x & 1); // 0..63, 64-query tiles

    __shared__ float LDSf[16][2][16][68];   // 139.3 KB (reduce only)
    __shared__ float LDSl[16][4][16];       // 4 KB

    // Q as B-fragments (loop-invariant): B[k=d][n=q]
    bf16x8 qfb[2][4];
    #pragma unroll
    for (int ks = 0; ks < 2; ++ks)
        #pragma unroll
        for (int ct = 0; ct < 4; ++ct)
            qfb[ks][ct] = *reinterpret_cast<const bf16x8*>(
                &Qw[((size_t)(b * SEQ + qt * 64 + ct * 16 + l16)) * DK + ks * 32 + quad * 8]);

    // per-lane base pointers
    const unsigned short* Kp = Kw + ((size_t)(b * SEQ) + wk * 16 + l16) * DK;
    const unsigned short* Vp[4];
    #pragma unroll
    for (int ct = 0; ct < 4; ++ct)
        Vp[ct] = Vtw + ((size_t)(b * 64 + ct * 16 + l16)) * SEQ + wk * 16 + quad * 4;

    // prologue: fragments for first tile (t = wp)
    bf16x8 kf_c0 = *reinterpret_cast<const bf16x8*>(Kp + (size_t)wp * 64 * DK + quad * 8);
    bf16x8 kf_c1 = *reinterpret_cast<const bf16x8*>(Kp + (size_t)wp * 64 * DK + 32 + quad * 8);
    bf16x4 va_c[4];
    #pragma unroll
    for (int ct = 0; ct < 4; ++ct)
        va_c[ct] = *reinterpret_cast<const bf16x4*>(Vp[ct] + (size_t)wp * 64);

    float lp[4] = {0.f, 0.f, 0.f, 0.f};
    f32x4 o[4][4] = {};   // o[ct_d][ct_q]

    #pragma unroll 1
    for (int i = 0; i < 16; ++i) {
        // prefetch next tile's fragments into fresh registers
        bf16x8 kf_n0, kf_n1;
        bf16x4 va_n[4];
        if (i < 15) {
            const size_t koff = (size_t)(4 * (i + 1) + wp) * 64;
            kf_n0 = *reinterpret_cast<const bf16x8*>(Kp + koff * DK + quad * 8);
            kf_n1 = *reinterpret_cast<const bf16x8*>(Kp + koff * DK + 32 + quad * 8);
            #pragma unroll
            for (int ct = 0; ct < 4; ++ct)
                va_n[ct] = *reinterpret_cast<const bf16x4*>(Vp[ct] + koff);
        }

        // S^T = K @ Q^T : C row = key_local = quad*4+r, col = q = ct*16+l16
        f32x4 sacc[4] = {};
        #pragma unroll
        for (int ct = 0; ct < 4; ++ct) {
            sacc[ct] = __builtin_amdgcn_mfma_f32_16x16x32_bf16(kf_c0, qfb[0][ct], sacc[ct], 0, 0, 0);
            sacc[ct] = __builtin_amdgcn_mfma_f32_16x16x32_bf16(kf_c1, qfb[1][ct], sacc[ct], 0, 0, 0);
        }

        // p = exp2(s) via v_exp_f32 (log2e folded into K scale); P^T feeds PV B-operand
        #pragma unroll
        for (int cq = 0; cq < 4; ++cq) {
            float p0 = __builtin_amdgcn_exp2f(sacc[cq][0]);
            float p1 = __builtin_amdgcn_exp2f(sacc[cq][1]);
            float p2 = __builtin_amdgcn_exp2f(sacc[cq][2]);
            float p3 = __builtin_amdgcn_exp2f(sacc[cq][3]);
            lp[cq] += (p0 + p1) + (p2 + p3);
            union { unsigned int u[2]; bf16x4 v; } pbu;
            pbu.u[0] = cvtpk(p0, p1);
            pbu.u[1] = cvtpk(p2, p3);
            bf16x4 pb = pbu.v;
            #pragma unroll
            for (int cd = 0; cd < 4; ++cd)
                o[cd][cq] = __builtin_amdgcn_mfma_f32_16x16x16bf16_1k(va_c[cd], pb, o[cd][cq], 0, 0, 0);
        }

        kf_c0 = kf_n0; kf_c1 = kf_n1;
        #pragma unroll
        for (int ct = 0; ct < 4; ++ct) va_c[ct] = va_n[ct];
    }

    // l: reduce across quads (wave's 16 keys), publish per wave
    #pragma unroll
    for (int cq = 0; cq < 4; ++cq) {
        float t = lp[cq];
        t += __shfl_xor(t, 16, 64);
        t += __shfl_xor(t, 32, 64);
        lp[cq] = t;
    }
    if (lane < 16)
        #pragma unroll
        for (int cq = 0; cq < 4; ++cq)
            LDSl[w][cq][lane] = lp[cq];

    // cross-wave O reduction + normalize + store: 2 rounds x 2 q-tiles (512 worker threads)
    #pragma unroll
    for (int rr = 0; rr < 2; ++rr) {
        #pragma unroll
        for (int hh = 0; hh < 2; ++hh)
            #pragma unroll
            for (int cd = 0; cd < 4; ++cd)
                *reinterpret_cast<f32x4*>(&LDSf[w][hh][l16][cd * 16 + quad * 4]) = o[cd][rr * 2 + hh];
        __syncthreads();
        if (tid < 512) {
            const int hh = tid >> 8;
            const int cq = rr * 2 + hh;
            const int ql = (tid >> 4) & 15;
            const int d4 = (tid & 15) << 2;
            f32x4 acc = {};
            #pragma unroll
            for (int w2 = 0; w2 < 16; ++w2)
                acc += *reinterpret_cast<const f32x4*>(&LDSf[w2][hh][ql][d4]);
            float lq = 0.f;
            #pragma unroll
            for (int w2 = 0; w2 < 16; ++w2)
                lq += LDSl[w2][cq][ql];
            f32x4 res = acc * (1.0f / lq);
            *reinterpret_cast<f32x4*>(&out[((size_t)(b * SEQ + qt * 64 + cq * 16 + ql)) * DK + d4]) = res;
        }
        __syncthreads();
    }
}

extern "C" void kernel_launch(void* const* d_in, const int* in_sizes, int n_in,
                              void* d_out, int out_size, void* d_ws, size_t ws_size,
                              hipStream_t stream) {
    const float* input1 = (const float*)d_in[0];
    const float* input2 = (const float*)d_in[1];
    const float* Wq = (const float*)d_in[2];
    const float* bq = (const float*)d_in[3];
    const float* Wk = (const float*)d_in[4];
    const float* bk = (const float*)d_in[5];
    const float* Wv = (const float*)d_in[6];
    const float* bv = (const float*)d_in[7];
    float* out = (float*)d_out;

    char* ws = (char*)d_ws;
    unsigned short* wtq = (unsigned short*)(ws + 0);
    unsigned short* wtk = (unsigned short*)(ws + 131072);
    unsigned short* wtv = (unsigned short*)(ws + 262144);
    unsigned short* Qw  = (unsigned short*)(ws + 393216);
    unsigned short* Kw  = (unsigned short*)(ws + 2490368);
    unsigned short* Vtw = (unsigned short*)(ws + 4587520);

    wt_kernel<<<dim3(16, 3), 256, 0, stream>>>(Wq, Wk, Wv, wtq, wtk, wtv);
    proj_kernel<<<dim3(256, 2), 256, 0, stream>>>(input2, input1, wtq, wtk, wtv,
                                                  bq, bk, bv, Qw, Kw, Vtw);
    attn_kernel<<<dim3(256), 1024, 0, stream>>>(Qw, Kw, Vtw, out);
}

// Round 4
// 210.872 us; speedup vs baseline: 1.2577x; 1.2577x over previous
//
#include <hip/hip_runtime.h>
#include <hip/hip_bf16.h>

#define E 1024
#define DK 64
#define SEQ 4096
#define NB 4
// 0.125 * log2(e): scores arrive pre-multiplied so softmax = exp2(s) = v_exp_f32
#define KSCALE 0.18033688011112042f

typedef short bf16x8 __attribute__((ext_vector_type(8)));
typedef short bf16x4 __attribute__((ext_vector_type(4)));
typedef float f32x4 __attribute__((ext_vector_type(4)));
typedef unsigned short u16x8 __attribute__((ext_vector_type(8)));

typedef const __attribute__((address_space(1))) unsigned int* gcp;
typedef __attribute__((address_space(3))) unsigned int* lcp;

__device__ inline unsigned short f2bf(float f) {
    unsigned int u = __float_as_uint(f);
    u += 0x7fff + ((u >> 16) & 1);   // round-to-nearest-even
    return (unsigned short)(u >> 16);
}
__device__ inline unsigned int cvtpk(float a, float b) {
    union { __hip_bfloat162 h; unsigned int u; } x;
    x.h = __float22bfloat162_rn(make_float2(a, b));
    return x.u;
}
__device__ inline bf16x8 cvt8(f32x4 a, f32x4 b) {
    union { unsigned int u[4]; bf16x8 v; } x;
    x.u[0] = cvtpk(a[0], a[1]); x.u[1] = cvtpk(a[2], a[3]);
    x.u[2] = cvtpk(b[0], b[1]); x.u[3] = cvtpk(b[2], b[3]);
    return x.v;
}

// ---------------- Kernel 0: W [1024][64] fp32 -> Wt [64][1024] bf16 (LDS transpose) --------
__global__ __launch_bounds__(256) void wt_kernel(
    const float* __restrict__ Wq, const float* __restrict__ Wk, const float* __restrict__ Wv,
    unsigned short* __restrict__ wtq, unsigned short* __restrict__ wtk, unsigned short* __restrict__ wtv)
{
    const float* src; unsigned short* dst;
    if (blockIdx.y == 0)      { src = Wq; dst = wtq; }
    else if (blockIdx.y == 1) { src = Wk; dst = wtk; }
    else                      { src = Wv; dst = wtv; }
    const int tid = threadIdx.x;
    const int e0 = blockIdx.x * 64;
    __shared__ float Ws[64][65];
    #pragma unroll
    for (int i = 0; i < 4; ++i) {
        int flat = i * 256 + tid;
        int r = flat >> 4;
        int c4 = (flat & 15) << 2;
        float4 v = *reinterpret_cast<const float4*>(&src[(size_t)(e0 + r) * DK + c4]);
        Ws[c4 + 0][r] = v.x; Ws[c4 + 1][r] = v.y; Ws[c4 + 2][r] = v.z; Ws[c4 + 3][r] = v.w;
    }
    __syncthreads();
    #pragma unroll
    for (int i = 0; i < 4; ++i) {
        int flat = i * 256 + tid;
        int c = flat >> 4;
        int r4 = (flat & 15) << 2;
        ushort4 o;
        o.x = f2bf(Ws[c][r4 + 0]); o.y = f2bf(Ws[c][r4 + 1]);
        o.z = f2bf(Ws[c][r4 + 2]); o.w = f2bf(Ws[c][r4 + 3]);
        *reinterpret_cast<ushort4*>(&dst[(size_t)c * E + e0 + r4]) = o;
    }
}

// ---------------- Kernel 1: QKV projection — DMA-staged A tiles + LDS-coalesced epilogue --
// R2 counters (48.5us): MfmaUtil 4.5 / VALU 7.5 / HBM 19% -> nothing busy; the per-lane A
// loads scatter 16 lanes over 16 rows at 4KB stride (~16-64 transactions/instr). Fix (same
// cure as attn R2): stage each 64x64-f32 A tile into double-buffered LDS via
// global_load_lds width=16 — each DMA instr covers 4 full contiguous 256B row segments.
// 16B-chunk XOR swizzle phys = cc ^ (row&15) on global source + read side (linear LDS dest)
// -> conflict-free ds_read_b128. A dbuf (32KB) aliased with the epilogue staging buffers;
// LDS total 64KB -> 2 blocks/CU. Arithmetic order identical to the verified kernel.
__global__ __launch_bounds__(256, 4) void proj_kernel(
    const float* __restrict__ in_q, const float* __restrict__ in_kv,
    const unsigned short* __restrict__ wtq, const unsigned short* __restrict__ wtk,
    const unsigned short* __restrict__ wtv,
    const float* __restrict__ bq, const float* __restrict__ bk, const float* __restrict__ bv,
    unsigned short* __restrict__ Qw, unsigned short* __restrict__ Kw, unsigned short* __restrict__ Vtw)
{
    const int tid = threadIdx.x;
    const int w = tid >> 6, lane = tid & 63, quad = lane >> 4, l16 = lane & 15;
    const int row0 = blockIdx.x * 64;
    const bool isQ = (blockIdx.y == 0);
    const float* A0 = isQ ? in_q : in_kv;
    const unsigned short* w0 = isQ ? wtq : wtk;

    __shared__ unsigned short W0s[2][4096];   // 16 KB
    __shared__ unsigned short W1s[2][4096];   // 16 KB
    __shared__ char ABuf[32768];              // main loop: A[2][64][64] f32 (swizzled)
                                              // epilogue:  Cs0[64][72] + Cs1[64][72] bf16

    const int rl = lane >> 3, pp = lane & 7;

    // ---- A DMA geometry: instr g = w*4+i covers LDS bytes [g*1024,+1024) = rows 4g+(l>>4),
    // phys 16B-chunk l&15; logical chunk cc = (l&15)^(row&15); src = full contiguous rows.
    const int ar = (w * 4) * 4 + (lane >> 4);          // row for i=0; i adds 4 rows
    auto stageA = [&](int kb, int bb) {
        #pragma unroll
        for (int i = 0; i < 4; ++i) {
            int g = w * 4 + i;
            int r = ar + i * 4;
            int cc = (lane & 15) ^ (r & 15);
            __builtin_amdgcn_global_load_lds(
                (gcp)(const void*)(A0 + (size_t)(row0 + r) * E + kb * 64 + cc * 4),
                (lcp)(void*)(ABuf + bb * 16384 + g * 1024), 16, 0, 0);
        }
    };

    // ---- prime: W + A tiles for kb=0 (async) ----
    #pragma unroll
    for (int i = 0; i < 2; ++i) {
        int g = w * 2 + i;
        int r = g * 8 + rl;
        int lc = pp ^ (r & 7);
        __builtin_amdgcn_global_load_lds((gcp)(const void*)(w0 + (size_t)r * E + lc * 8),
                                         (lcp)(void*)&W0s[0][g * 512], 16, 0, 0);
        if (!isQ)
            __builtin_amdgcn_global_load_lds((gcp)(const void*)(wtv + (size_t)r * E + lc * 8),
                                             (lcp)(void*)&W1s[0][g * 512], 16, 0, 0);
    }
    stageA(0, 0);
    __syncthreads();

    f32x4 acc0[4] = {};
    f32x4 acc1[4] = {};

    const int arow = w * 16 + l16;                     // this lane's A row (in-tile)
    const char* Arow_lds = ABuf + arow * 256;

    for (int kb = 0; kb < 16; ++kb) {
        const int cur = kb & 1, nxt = cur ^ 1;
        if (kb < 15) {
            const int ko = (kb + 1) * 64;
            #pragma unroll
            for (int i = 0; i < 2; ++i) {
                int g = w * 2 + i;
                int r = g * 8 + rl;
                int lc = pp ^ (r & 7);
                __builtin_amdgcn_global_load_lds((gcp)(const void*)(w0 + (size_t)r * E + ko + lc * 8),
                                                 (lcp)(void*)&W0s[nxt][g * 512], 16, 0, 0);
                if (!isQ)
                    __builtin_amdgcn_global_load_lds((gcp)(const void*)(wtv + (size_t)r * E + ko + lc * 8),
                                                     (lcp)(void*)&W1s[nxt][g * 512], 16, 0, 0);
            }
            stageA(kb + 1, nxt);
        }
        // compute on cur: A fragments from LDS (XOR-swizzled), W from LDS
        #pragma unroll
        for (int ks = 0; ks < 2; ++ks) {
            f32x4 a0 = *reinterpret_cast<const f32x4*>(
                Arow_lds + cur * 16384 + ((ks * 8 + quad * 2 + 0) ^ l16) * 16);
            f32x4 a1 = *reinterpret_cast<const f32x4*>(
                Arow_lds + cur * 16384 + ((ks * 8 + quad * 2 + 1) ^ l16) * 16);
            bf16x8 af = cvt8(a0, a1);
            #pragma unroll
            for (int ct = 0; ct < 4; ++ct) {
                int brow = ct * 16 + l16;
                int pc = (ks * 4 + quad) ^ (brow & 7);
                bf16x8 b0 = *reinterpret_cast<const bf16x8*>(&W0s[cur][brow * 64 + pc * 8]);
                acc0[ct] = __builtin_amdgcn_mfma_f32_16x16x32_bf16(af, b0, acc0[ct], 0, 0, 0);
                if (!isQ) {
                    bf16x8 b1 = *reinterpret_cast<const bf16x8*>(&W1s[cur][brow * 64 + pc * 8]);
                    acc1[ct] = __builtin_amdgcn_mfma_f32_16x16x32_bf16(af, b1, acc1[ct], 0, 0, 0);
                }
            }
        }
        __syncthreads();   // covers W/A dbuf swap (and last-iter compute before aliasing)
    }

    // ---- epilogue: C/D layout col=lane&15, row=quad*4+reg. Stage in LDS (aliased onto
    // ABuf, stride 72 shorts = 144B keeps 16B alignment), then store coalesced 128B rows.
    unsigned short (*Cs0)[72] = reinterpret_cast<unsigned short(*)[72]>(ABuf);
    unsigned short (*Cs1)[72] = reinterpret_cast<unsigned short(*)[72]>(ABuf + 9216);
    const int tl0 = w * 16 + quad * 4;                     // token-local base
    #pragma unroll
    for (int ct = 0; ct < 4; ++ct) {
        int col = ct * 16 + l16;
        if (isQ) {
            float bias = bq[col];
            #pragma unroll
            for (int r = 0; r < 4; ++r)
                Cs0[tl0 + r][col] = f2bf(acc0[ct][r] + bias);
        } else {
            float biask = bk[col], biasv = bv[col];
            #pragma unroll
            for (int r = 0; r < 4; ++r) {
                Cs0[tl0 + r][col] = f2bf((acc0[ct][r] + biask) * KSCALE);
                Cs1[col][tl0 + r] = f2bf(acc1[ct][r] + biasv);
            }
        }
    }
    __syncthreads();

    // coalesced stores: wave w handles rows w*16..w*16+15, 128B per row
    const int bb = row0 >> 12, tok0 = row0 & 4095;
    #pragma unroll
    for (int jj = 0; jj < 2; ++jj) {
        int rr = w * 16 + jj * 8 + (lane >> 3);
        int c8 = (lane & 7) * 8;
        u16x8 v0 = *reinterpret_cast<const u16x8*>(&Cs0[rr][c8]);
        if (isQ) {
            *reinterpret_cast<u16x8*>(&Qw[(size_t)(row0 + rr) * DK + c8]) = v0;
        } else {
            *reinterpret_cast<u16x8*>(&Kw[(size_t)(row0 + rr) * DK + c8]) = v0;
            u16x8 v1 = *reinterpret_cast<const u16x8*>(&Cs1[rr][c8]);
            *reinterpret_cast<u16x8*>(&Vtw[((size_t)(bb * 64 + rr)) * SEQ + tok0 + c8]) = v1;
        }
    }
}

// ---------------- Kernel 2: flash attention — LDS-staged K/V (DMA), R2 version verbatim --
// Best measured attn (~49us). R3's 1024-thread variant spilled (VGPR capped at 64, 47MB
// scratch traffic) — reverted. grid 256 x 512 threads (8 waves), 64 q/block; 128-key tiles
// staged into double-buffered LDS via global_load_lds width=16 with XOR chunk swizzle.
__global__ __launch_bounds__(512) void attn_kernel(
    const unsigned short* __restrict__ Qw, const unsigned short* __restrict__ Kw,
    const unsigned short* __restrict__ Vtw, float* __restrict__ out)
{
    const int tid = threadIdx.x;
    const int w = tid >> 6, lane = tid & 63, quad = lane >> 4, l16 = lane & 15;
    const int wk = w & 3, wp = w >> 2;
    const int b = (blockIdx.x & 7) >> 1;                        // XCD-aware: 2 MB K/V per XCD
    const int qt = ((blockIdx.x >> 3) << 1) | (blockIdx.x & 1); // 0..63, 64-query tiles

    __shared__ unsigned short Klds[2][8192];   // [buf][key*64 + d], swizzled, 16 KB each
    __shared__ unsigned short Vlds[2][8192];   // [buf][d*128 + key], swizzled, 16 KB each
    __shared__ float LDSf[8][2][16][68];       // 68 KB (reduce only)
    __shared__ float LDSl[8][4][16];

    const unsigned short* Ksrc = Kw + (size_t)b * SEQ * DK;     // rows of 128B
    const unsigned short* Vsrc = Vtw + (size_t)b * 64 * SEQ;    // rows of 8192B

    const int g0 = w * 2, g1 = w * 2 + 1;
    const int krow0 = g0 * 8 + (lane >> 3), krow1 = g1 * 8 + (lane >> 3);
    const int kcol = ((lane & 7) ^ (lane >> 3)) << 4;
    const int vrow0 = g0 * 4 + (lane >> 4), vrow1 = g1 * 4 + (lane >> 4);
    const int vcol0 = ((lane & 15) ^ (vrow0 & 7)) << 4;
    const int vcol1 = ((lane & 15) ^ (vrow1 & 7)) << 4;

    auto stage = [&](int t, int bb) {
        const char* kb = (const char*)Ksrc + (size_t)t * 16384;
        __builtin_amdgcn_global_load_lds((gcp)(const void*)(kb + krow0 * 128 + kcol),
                                         (lcp)(void*)((char*)Klds[bb] + g0 * 1024), 16, 0, 0);
        __builtin_amdgcn_global_load_lds((gcp)(const void*)(kb + krow1 * 128 + kcol),
                                         (lcp)(void*)((char*)Klds[bb] + g1 * 1024), 16, 0, 0);
        const char* vb = (const char*)Vsrc + t * 256;
        __builtin_amdgcn_global_load_lds((gcp)(const void*)(vb + (size_t)vrow0 * 8192 + vcol0),
                                         (lcp)(void*)((char*)Vlds[bb] + g0 * 1024), 16, 0, 0);
        __builtin_amdgcn_global_load_lds((gcp)(const void*)(vb + (size_t)vrow1 * 8192 + vcol1),
                                         (lcp)(void*)((char*)Vlds[bb] + g1 * 1024), 16, 0, 0);
    };

    stage(0, 0);   // prime tile 0 while Q loads are in flight

    bf16x8 qfb[2][4];
    #pragma unroll
    for (int ks = 0; ks < 2; ++ks)
        #pragma unroll
        for (int ct = 0; ct < 4; ++ct)
            qfb[ks][ct] = *reinterpret_cast<const bf16x8*>(
                &Qw[((size_t)(b * SEQ + qt * 64 + ct * 16 + l16)) * DK + ks * 32 + quad * 8]);

    const int kxor = (l16 & 7) << 4;
    const int krow = wp * 64 + wk * 16 + l16;
    const unsigned kf0_off = (unsigned)(krow * 128 + ((quad * 16) ^ kxor));
    const unsigned kf1_off = (unsigned)(krow * 128 + ((64 + quad * 16) ^ kxor));
    unsigned va_off[4];
    #pragma unroll
    for (int ct = 0; ct < 4; ++ct)
        va_off[ct] = (unsigned)((ct * 16 + l16) * 256 +
                                ((wp * 128 + wk * 32 + quad * 8) ^ kxor));

    __syncthreads();

    float lp[4] = {0.f, 0.f, 0.f, 0.f};
    f32x4 o[4][4] = {};   // o[ct_d][ct_q]

    #pragma unroll 2
    for (int i = 0; i < 32; ++i) {
        const int cur = i & 1;
        if (i < 31) stage(i + 1, cur ^ 1);

        bf16x8 kf0 = *reinterpret_cast<const bf16x8*>((const char*)Klds[cur] + kf0_off);
        bf16x8 kf1 = *reinterpret_cast<const bf16x8*>((const char*)Klds[cur] + kf1_off);
        bf16x4 va[4];
        #pragma unroll
        for (int ct = 0; ct < 4; ++ct)
            va[ct] = *reinterpret_cast<const bf16x4*>((const char*)Vlds[cur] + va_off[ct]);

        f32x4 sacc[4] = {};
        #pragma unroll
        for (int ct = 0; ct < 4; ++ct) {
            sacc[ct] = __builtin_amdgcn_mfma_f32_16x16x32_bf16(kf0, qfb[0][ct], sacc[ct], 0, 0, 0);
            sacc[ct] = __builtin_amdgcn_mfma_f32_16x16x32_bf16(kf1, qfb[1][ct], sacc[ct], 0, 0, 0);
        }

        #pragma unroll
        for (int cq = 0; cq < 4; ++cq) {
            float p0 = __builtin_amdgcn_exp2f(sacc[cq][0]);
            float p1 = __builtin_amdgcn_exp2f(sacc[cq][1]);
            float p2 = __builtin_amdgcn_exp2f(sacc[cq][2]);
            float p3 = __builtin_amdgcn_exp2f(sacc[cq][3]);
            lp[cq] += (p0 + p1) + (p2 + p3);
            union { unsigned int u[2]; bf16x4 v; } pbu;
            pbu.u[0] = cvtpk(p0, p1);
            pbu.u[1] = cvtpk(p2, p3);
            bf16x4 pb = pbu.v;
            #pragma unroll
            for (int cd = 0; cd < 4; ++cd)
                o[cd][cq] = __builtin_amdgcn_mfma_f32_16x16x16bf16_1k(va[cd], pb, o[cd][cq], 0, 0, 0);
        }

        __syncthreads();
    }

    #pragma unroll
    for (int cq = 0; cq < 4; ++cq) {
        float t = lp[cq];
        t += __shfl_xor(t, 16, 64);
        t += __shfl_xor(t, 32, 64);
        lp[cq] = t;
    }
    if (lane < 16)
        #pragma unroll
        for (int cq = 0; cq < 4; ++cq)
            LDSl[w][cq][lane] = lp[cq];

    #pragma unroll
    for (int rr = 0; rr < 2; ++rr) {
        #pragma unroll
        for (int hh = 0; hh < 2; ++hh)
            #pragma unroll
            for (int cd = 0; cd < 4; ++cd)
                *reinterpret_cast<f32x4*>(&LDSf[w][hh][l16][cd * 16 + quad * 4]) = o[cd][rr * 2 + hh];
        __syncthreads();
        {
            const int hh = tid >> 8;
            const int cq = rr * 2 + hh;
            const int ql = (tid >> 4) & 15;
            const int d4 = (tid & 15) << 2;
            f32x4 acc = {};
            #pragma unroll
            for (int w2 = 0; w2 < 8; ++w2)
                acc += *reinterpret_cast<const f32x4*>(&LDSf[w2][hh][ql][d4]);
            float lq = 0.f;
            #pragma unroll
            for (int w2 = 0; w2 < 8; ++w2)
                lq += LDSl[w2][cq][ql];
            f32x4 res = acc * (1.0f / lq);
            *reinterpret_cast<f32x4*>(&out[((size_t)(b * SEQ + qt * 64 + cq * 16 + ql)) * DK + d4]) = res;
        }
        __syncthreads();
    }
}

extern "C" void kernel_launch(void* const* d_in, const int* in_sizes, int n_in,
                              void* d_out, int out_size, void* d_ws, size_t ws_size,
                              hipStream_t stream) {
    const float* input1 = (const float*)d_in[0];
    const float* input2 = (const float*)d_in[1];
    const float* Wq = (const float*)d_in[2];
    const float* bq = (const float*)d_in[3];
    const float* Wk = (const float*)d_in[4];
    const float* bk = (const float*)d_in[5];
    const float* Wv = (const float*)d_in[6];
    const float* bv = (const float*)d_in[7];
    float* out = (float*)d_out;

    char* ws = (char*)d_ws;
    unsigned short* wtq = (unsigned short*)(ws + 0);
    unsigned short* wtk = (unsigned short*)(ws + 131072);
    unsigned short* wtv = (unsigned short*)(ws + 262144);
    unsigned short* Qw  = (unsigned short*)(ws + 393216);
    unsigned short* Kw  = (unsigned short*)(ws + 2490368);
    unsigned short* Vtw = (unsigned short*)(ws + 4587520);

    wt_kernel<<<dim3(16, 3), 256, 0, stream>>>(Wq, Wk, Wv, wtq, wtk, wtv);
    proj_kernel<<<dim3(256, 2), 256, 0, stream>>>(input2, input1, wtq, wtk, wtv,
                                                  bq, bk, bv, Qw, Kw, Vtw);
    attn_kernel<<<dim3(256), 512, 0, stream>>>(Qw, Kw, Vtw, out);
}

// Round 5
// 197.155 us; speedup vs baseline: 1.3452x; 1.0696x over previous
//
#include <hip/hip_runtime.h>
#include <hip/hip_bf16.h>

#define E 1024
#define DK 64
#define SEQ 4096
#define NB 4
// 0.125 * log2(e): scores arrive pre-multiplied so softmax = exp2(s) = v_exp_f32
#define KSCALE 0.18033688011112042f

typedef short bf16x8 __attribute__((ext_vector_type(8)));
typedef short bf16x4 __attribute__((ext_vector_type(4)));
typedef float f32x4 __attribute__((ext_vector_type(4)));

typedef const __attribute__((address_space(1))) unsigned int* gcp;
typedef __attribute__((address_space(3))) unsigned int* lcp;

__device__ inline unsigned short f2bf(float f) {
    unsigned int u = __float_as_uint(f);
    u += 0x7fff + ((u >> 16) & 1);   // round-to-nearest-even
    return (unsigned short)(u >> 16);
}
__device__ inline unsigned int cvtpk(float a, float b) {
    union { __hip_bfloat162 h; unsigned int u; } x;
    x.h = __float22bfloat162_rn(make_float2(a, b));
    return x.u;
}
__device__ inline bf16x8 cvt8(f32x4 a, f32x4 b) {
    union { unsigned int u[4]; bf16x8 v; } x;
    x.u[0] = cvtpk(a[0], a[1]); x.u[1] = cvtpk(a[2], a[3]);
    x.u[2] = cvtpk(b[0], b[1]); x.u[3] = cvtpk(b[2], b[3]);
    return x.v;
}

// ---------------- Kernel 0: W [1024][64] fp32 -> Wt [64][1024] bf16 (LDS transpose) --------
__global__ __launch_bounds__(256) void wt_kernel(
    const float* __restrict__ Wq, const float* __restrict__ Wk, const float* __restrict__ Wv,
    unsigned short* __restrict__ wtq, unsigned short* __restrict__ wtk, unsigned short* __restrict__ wtv)
{
    const float* src; unsigned short* dst;
    if (blockIdx.y == 0)      { src = Wq; dst = wtq; }
    else if (blockIdx.y == 1) { src = Wk; dst = wtk; }
    else                      { src = Wv; dst = wtv; }
    const int tid = threadIdx.x;
    const int e0 = blockIdx.x * 64;
    __shared__ float Ws[64][65];
    #pragma unroll
    for (int i = 0; i < 4; ++i) {
        int flat = i * 256 + tid;
        int r = flat >> 4;
        int c4 = (flat & 15) << 2;
        float4 v = *reinterpret_cast<const float4*>(&src[(size_t)(e0 + r) * DK + c4]);
        Ws[c4 + 0][r] = v.x; Ws[c4 + 1][r] = v.y; Ws[c4 + 2][r] = v.z; Ws[c4 + 3][r] = v.w;
    }
    __syncthreads();
    #pragma unroll
    for (int i = 0; i < 4; ++i) {
        int flat = i * 256 + tid;
        int c = flat >> 4;
        int r4 = (flat & 15) << 2;
        ushort4 o;
        o.x = f2bf(Ws[c][r4 + 0]); o.y = f2bf(Ws[c][r4 + 1]);
        o.z = f2bf(Ws[c][r4 + 2]); o.w = f2bf(Ws[c][r4 + 3]);
        *reinterpret_cast<ushort4*>(&dst[(size_t)c * E + e0 + r4]) = o;
    }
}

// ---------------- Kernel 1: QKV projection — R2-exact (best measured 48.5us) --------------
// R4's A-LDS-staging regressed (ds_read + DMA drain on critical path, +bank conflicts);
// reverted to register-prefetched A + async W dbuf.
__global__ __launch_bounds__(256, 4) void proj_kernel(
    const float* __restrict__ in_q, const float* __restrict__ in_kv,
    const unsigned short* __restrict__ wtq, const unsigned short* __restrict__ wtk,
    const unsigned short* __restrict__ wtv,
    const float* __restrict__ bq, const float* __restrict__ bk, const float* __restrict__ bv,
    unsigned short* __restrict__ Qw, unsigned short* __restrict__ Kw, unsigned short* __restrict__ Vtw)
{
    const int tid = threadIdx.x;
    const int w = tid >> 6, lane = tid & 63, quad = lane >> 4, l16 = lane & 15;
    const int row0 = blockIdx.x * 64;
    const bool isQ = (blockIdx.y == 0);
    const float* Arow = (isQ ? in_q : in_kv) + (size_t)(row0 + w * 16 + l16) * E;
    const unsigned short* w0 = isQ ? wtq : wtk;

    __shared__ unsigned short W0s[2][4096];   // 16 KB
    __shared__ unsigned short W1s[2][4096];   // 16 KB

    const int rl = lane >> 3, pp = lane & 7;

    #pragma unroll
    for (int i = 0; i < 2; ++i) {
        int g = w * 2 + i;
        int r = g * 8 + rl;
        int lc = pp ^ (r & 7);
        __builtin_amdgcn_global_load_lds((gcp)(const void*)(w0 + (size_t)r * E + lc * 8),
                                         (lcp)(void*)&W0s[0][g * 512], 16, 0, 0);
        if (!isQ)
            __builtin_amdgcn_global_load_lds((gcp)(const void*)(wtv + (size_t)r * E + lc * 8),
                                             (lcp)(void*)&W1s[0][g * 512], 16, 0, 0);
    }
    f32x4 a_cur[4];
    #pragma unroll
    for (int ks = 0; ks < 2; ++ks)
        #pragma unroll
        for (int j = 0; j < 2; ++j)
            a_cur[ks * 2 + j] = *reinterpret_cast<const f32x4*>(Arow + ks * 32 + quad * 8 + j * 4);
    __syncthreads();

    f32x4 acc0[4] = {};
    f32x4 acc1[4] = {};

    for (int kb = 0; kb < 16; ++kb) {
        const int cur = kb & 1, nxt = cur ^ 1;
        f32x4 a_nxt[4];
        if (kb < 15) {
            const int ko = (kb + 1) * 64;
            #pragma unroll
            for (int i = 0; i < 2; ++i) {
                int g = w * 2 + i;
                int r = g * 8 + rl;
                int lc = pp ^ (r & 7);
                __builtin_amdgcn_global_load_lds((gcp)(const void*)(w0 + (size_t)r * E + ko + lc * 8),
                                                 (lcp)(void*)&W0s[nxt][g * 512], 16, 0, 0);
                if (!isQ)
                    __builtin_amdgcn_global_load_lds((gcp)(const void*)(wtv + (size_t)r * E + ko + lc * 8),
                                                     (lcp)(void*)&W1s[nxt][g * 512], 16, 0, 0);
            }
            const float* an = Arow + ko;
            #pragma unroll
            for (int ks = 0; ks < 2; ++ks)
                #pragma unroll
                for (int j = 0; j < 2; ++j)
                    a_nxt[ks * 2 + j] = *reinterpret_cast<const f32x4*>(an + ks * 32 + quad * 8 + j * 4);
        }
        #pragma unroll
        for (int ks = 0; ks < 2; ++ks) {
            bf16x8 af = cvt8(a_cur[ks * 2], a_cur[ks * 2 + 1]);
            #pragma unroll
            for (int ct = 0; ct < 4; ++ct) {
                int brow = ct * 16 + l16;
                int pc = (ks * 4 + quad) ^ (brow & 7);
                bf16x8 b0 = *reinterpret_cast<const bf16x8*>(&W0s[cur][brow * 64 + pc * 8]);
                acc0[ct] = __builtin_amdgcn_mfma_f32_16x16x32_bf16(af, b0, acc0[ct], 0, 0, 0);
                if (!isQ) {
                    bf16x8 b1 = *reinterpret_cast<const bf16x8*>(&W1s[cur][brow * 64 + pc * 8]);
                    acc1[ct] = __builtin_amdgcn_mfma_f32_16x16x32_bf16(af, b1, acc1[ct], 0, 0, 0);
                }
            }
        }
        #pragma unroll
        for (int j = 0; j < 4; ++j) a_cur[j] = a_nxt[j];
        if (kb < 15) __syncthreads();
    }

    // epilogue: C/D layout col=lane&15, row=quad*4+reg
    const int orow0 = row0 + w * 16 + quad * 4;
    #pragma unroll
    for (int ct = 0; ct < 4; ++ct) {
        int col = ct * 16 + l16;
        if (isQ) {
            float bias = bq[col];
            #pragma unroll
            for (int r = 0; r < 4; ++r)
                Qw[(size_t)(orow0 + r) * DK + col] = f2bf(acc0[ct][r] + bias);
        } else {
            float biask = bk[col], biasv = bv[col];
            #pragma unroll
            for (int r = 0; r < 4; ++r) {
                int grow = orow0 + r;
                Kw[(size_t)grow * DK + col] = f2bf((acc0[ct][r] + biask) * KSCALE);
                int bb = grow >> 12;
                int tok = grow & 4095;
                Vtw[((size_t)(bb * 64 + col)) * SEQ + tok] = f2bf(acc1[ct][r] + biasv);
            }
        }
    }
}

// ---------------- Kernel 2: flash attention — q128 x key-half, LDS-shared K/V ------------
// Model from R0/R1/R2: attn time ~ total K/V bytes / ~5.2 TB/s regardless of structure.
// Fix = read fewer bytes: each block owns (q-tile 128) x (key half 2048). K/V tiles are
// DMA-staged ONCE per block and shared by both 64-q wave groups -> total K/V traffic
// halves (256->128 MB). grid 256 x 512 threads; wave w: q-half h=w>>2, key-slice s=w&3
// (32 keys of each 128-key tile, two 16-key substeps = R2's proven inner body). Max-free
// exp2 softmax => partials combine as (O0+O1)/(l0+l1) in a tiny epilogue kernel.
// blockIdx&7 <-> (kh,b): each XCD streams exactly one 512 KB K/V half from its L2.
__global__ __launch_bounds__(512) void attn_kernel(
    const unsigned short* __restrict__ Qw, const unsigned short* __restrict__ Kw,
    const unsigned short* __restrict__ Vtw, float* __restrict__ Opart, float* __restrict__ Lpart)
{
    const int tid = threadIdx.x;
    const int w = tid >> 6, lane = tid & 63, quad = lane >> 4, l16 = lane & 15;
    const int s = w & 3, h = w >> 2;
    const int kh = blockIdx.x & 1;                      // key half
    const int b  = (blockIdx.x >> 1) & 3;               // batch
    const int qt = blockIdx.x >> 3;                     // 0..31, 128-query tiles

    __shared__ unsigned short Klds[2][8192];   // [buf][key*64 + d], swizzled, 16 KB each
    __shared__ unsigned short Vlds[2][8192];   // [buf][d*128 + key], swizzled, 16 KB each
    __shared__ float LDSf[8][2][16][68];       // 69.6 KB (reduce only)
    __shared__ float LDSl[8][4][16];

    const unsigned short* Ksrc = Kw + ((size_t)b * SEQ + kh * 2048) * DK;   // rows of 128B
    const unsigned short* Vsrc = Vtw + (size_t)b * 64 * SEQ + kh * 2048;    // rows of 8192B

    // ---- DMA geometry (same as R2): wave w issues instrs g0,g1 for K and V per tile ----
    const int g0 = w * 2, g1 = w * 2 + 1;
    const int krow0 = g0 * 8 + (lane >> 3), krow1 = g1 * 8 + (lane >> 3);
    const int kcol = ((lane & 7) ^ (lane >> 3)) << 4;
    const int vrow0 = g0 * 4 + (lane >> 4), vrow1 = g1 * 4 + (lane >> 4);
    const int vcol0 = ((lane & 15) ^ (vrow0 & 7)) << 4;
    const int vcol1 = ((lane & 15) ^ (vrow1 & 7)) << 4;

    auto stage = [&](int t, int bb) {
        const char* kb = (const char*)Ksrc + (size_t)t * 16384;
        __builtin_amdgcn_global_load_lds((gcp)(const void*)(kb + krow0 * 128 + kcol),
                                         (lcp)(void*)((char*)Klds[bb] + g0 * 1024), 16, 0, 0);
        __builtin_amdgcn_global_load_lds((gcp)(const void*)(kb + krow1 * 128 + kcol),
                                         (lcp)(void*)((char*)Klds[bb] + g1 * 1024), 16, 0, 0);
        const char* vb = (const char*)Vsrc + t * 256;
        __builtin_amdgcn_global_load_lds((gcp)(const void*)(vb + (size_t)vrow0 * 8192 + vcol0),
                                         (lcp)(void*)((char*)Vlds[bb] + g0 * 1024), 16, 0, 0);
        __builtin_amdgcn_global_load_lds((gcp)(const void*)(vb + (size_t)vrow1 * 8192 + vcol1),
                                         (lcp)(void*)((char*)Vlds[bb] + g1 * 1024), 16, 0, 0);
    };

    stage(0, 0);   // prime tile 0 while Q loads are in flight

    // Q as B-fragments (loop-invariant): B[k=d][n=q], this wave's 64-q half
    bf16x8 qfb[2][4];
    #pragma unroll
    for (int ks = 0; ks < 2; ++ks)
        #pragma unroll
        for (int ct = 0; ct < 4; ++ct)
            qfb[ks][ct] = *reinterpret_cast<const bf16x8*>(
                &Qw[((size_t)(b * SEQ + qt * 128 + h * 64 + ct * 16 + l16)) * DK + ks * 32 + quad * 8]);

    // ---- read-side LDS offsets: two 16-key substeps of the wave's 32-key slice ----
    const int kxor = (l16 & 7) << 4;
    unsigned kf_off[2][2];
    unsigned va_off[2][4];
    #pragma unroll
    for (int t2 = 0; t2 < 2; ++t2) {
        const int kr = s * 32 + t2 * 16 + l16;
        kf_off[t2][0] = (unsigned)(kr * 128 + ((quad * 16) ^ kxor));
        kf_off[t2][1] = (unsigned)(kr * 128 + ((64 + quad * 16) ^ kxor));
        #pragma unroll
        for (int ct = 0; ct < 4; ++ct)
            va_off[t2][ct] = (unsigned)((ct * 16 + l16) * 256 +
                                        ((s * 64 + t2 * 32 + quad * 8) ^ kxor));
    }

    __syncthreads();

    float lp[4] = {0.f, 0.f, 0.f, 0.f};
    f32x4 o[4][4] = {};   // o[ct_d][ct_q]

    #pragma unroll 1
    for (int i = 0; i < 16; ++i) {
        const int cur = i & 1;
        if (i < 15) stage(i + 1, cur ^ 1);    // DMA next tile into other buffer

        #pragma unroll
        for (int t2 = 0; t2 < 2; ++t2) {
            bf16x8 kf0 = *reinterpret_cast<const bf16x8*>((const char*)Klds[cur] + kf_off[t2][0]);
            bf16x8 kf1 = *reinterpret_cast<const bf16x8*>((const char*)Klds[cur] + kf_off[t2][1]);
            bf16x4 va[4];
            #pragma unroll
            for (int ct = 0; ct < 4; ++ct)
                va[ct] = *reinterpret_cast<const bf16x4*>((const char*)Vlds[cur] + va_off[t2][ct]);

            // S^T = K @ Q^T : C row = key_local = quad*4+r, col = q = ct*16+l16
            f32x4 sacc[4] = {};
            #pragma unroll
            for (int ct = 0; ct < 4; ++ct) {
                sacc[ct] = __builtin_amdgcn_mfma_f32_16x16x32_bf16(kf0, qfb[0][ct], sacc[ct], 0, 0, 0);
                sacc[ct] = __builtin_amdgcn_mfma_f32_16x16x32_bf16(kf1, qfb[1][ct], sacc[ct], 0, 0, 0);
            }

            // p = exp2(s) (scale pre-folded into K); P^T feeds PV B-operand directly
            #pragma unroll
            for (int cq = 0; cq < 4; ++cq) {
                float p0 = __builtin_amdgcn_exp2f(sacc[cq][0]);
                float p1 = __builtin_amdgcn_exp2f(sacc[cq][1]);
                float p2 = __builtin_amdgcn_exp2f(sacc[cq][2]);
                float p3 = __builtin_amdgcn_exp2f(sacc[cq][3]);
                lp[cq] += (p0 + p1) + (p2 + p3);
                union { unsigned int u[2]; bf16x4 v; } pbu;
                pbu.u[0] = cvtpk(p0, p1);
                pbu.u[1] = cvtpk(p2, p3);
                bf16x4 pb = pbu.v;
                #pragma unroll
                for (int cd = 0; cd < 4; ++cd)
                    o[cd][cq] = __builtin_amdgcn_mfma_f32_16x16x16bf16_1k(va[cd], pb, o[cd][cq], 0, 0, 0);
            }
        }

        __syncthreads();   // next tile staged (vmcnt drained) + everyone done with cur
    }

    // l: reduce across quads (wave's keys), publish per wave
    #pragma unroll
    for (int cq = 0; cq < 4; ++cq) {
        float t = lp[cq];
        t += __shfl_xor(t, 16, 64);
        t += __shfl_xor(t, 32, 64);
        lp[cq] = t;
    }
    if (lane < 16)
        #pragma unroll
        for (int cq = 0; cq < 4; ++cq)
            LDSl[w][cq][lane] = lp[cq];

    // cross-wave partial-O reduce (4 waves per q-half) + store partials (no normalize)
    const int rowbase = b * SEQ + qt * 128;
    #pragma unroll
    for (int rr = 0; rr < 2; ++rr) {
        #pragma unroll
        for (int hh = 0; hh < 2; ++hh)
            #pragma unroll
            for (int cd = 0; cd < 4; ++cd)
                *reinterpret_cast<f32x4*>(&LDSf[w][hh][l16][cd * 16 + quad * 4]) = o[cd][rr * 2 + hh];
        __syncthreads();
        #pragma unroll
        for (int p = 0; p < 2; ++p) {
            const int item = tid + p * 512;            // 1024 items: 2 halves x 2 cq x 16 q x 16 d4
            const int h2 = item >> 9, rem = item & 511;
            const int j = rem >> 8, ql = (rem >> 4) & 15, d4 = (rem & 15) << 2;
            const int cq = rr * 2 + j;
            f32x4 acc = {};
            #pragma unroll
            for (int w2 = 0; w2 < 4; ++w2)
                acc += *reinterpret_cast<const f32x4*>(&LDSf[h2 * 4 + w2][j][ql][d4]);
            const int row = rowbase + h2 * 64 + cq * 16 + ql;
            *reinterpret_cast<f32x4*>(&Opart[((size_t)kh * (NB * SEQ) + row) * DK + d4]) = acc;
            if ((rem & 15) == 0) {
                float lq = 0.f;
                #pragma unroll
                for (int w2 = 0; w2 < 4; ++w2)
                    lq += LDSl[h2 * 4 + w2][cq][ql];
                Lpart[kh * (NB * SEQ) + row] = lq;
            }
        }
        __syncthreads();
    }
}

// ---------------- Kernel 3: combine key-half partials: O = (O0+O1)/(l0+l1) ---------------
__global__ __launch_bounds__(256) void comb_kernel(
    const float* __restrict__ Op, const float* __restrict__ Lp, float* __restrict__ out)
{
    const int idx = blockIdx.x * 256 + threadIdx.x;     // 65536 threads, 262144 f32x4 chunks
    #pragma unroll
    for (int it = 0; it < 4; ++it) {
        const int c = idx + it * 65536;
        const int row = c >> 4;
        const int d4 = (c & 15) << 2;
        f32x4 a = *reinterpret_cast<const f32x4*>(&Op[(size_t)row * DK + d4]);
        f32x4 b2 = *reinterpret_cast<const f32x4*>(&Op[(size_t)(NB * SEQ + row) * DK + d4]);
        float l = Lp[row] + Lp[NB * SEQ + row];
        f32x4 r = (a + b2) * (1.0f / l);
        *reinterpret_cast<f32x4*>(&out[(size_t)row * DK + d4]) = r;
    }
}

extern "C" void kernel_launch(void* const* d_in, const int* in_sizes, int n_in,
                              void* d_out, int out_size, void* d_ws, size_t ws_size,
                              hipStream_t stream) {
    const float* input1 = (const float*)d_in[0];
    const float* input2 = (const float*)d_in[1];
    const float* Wq = (const float*)d_in[2];
    const float* bq = (const float*)d_in[3];
    const float* Wk = (const float*)d_in[4];
    const float* bk = (const float*)d_in[5];
    const float* Wv = (const float*)d_in[6];
    const float* bv = (const float*)d_in[7];
    float* out = (float*)d_out;

    char* ws = (char*)d_ws;
    unsigned short* wtq = (unsigned short*)(ws + 0);
    unsigned short* wtk = (unsigned short*)(ws + 131072);
    unsigned short* wtv = (unsigned short*)(ws + 262144);
    unsigned short* Qw  = (unsigned short*)(ws + 393216);
    unsigned short* Kw  = (unsigned short*)(ws + 2490368);
    unsigned short* Vtw = (unsigned short*)(ws + 4587520);
    float* Opart = (float*)(ws + 6684672);     // [2][16384][64] f32 = 8 MB
    float* Lpart = (float*)(ws + 15073280);    // [2][16384] f32 = 128 KB

    wt_kernel<<<dim3(16, 3), 256, 0, stream>>>(Wq, Wk, Wv, wtq, wtk, wtv);
    proj_kernel<<<dim3(256, 2), 256, 0, stream>>>(input2, input1, wtq, wtk, wtv,
                                                  bq, bk, bv, Qw, Kw, Vtw);
    attn_kernel<<<dim3(256), 512, 0, stream>>>(Qw, Kw, Vtw, Opart, Lpart);
    comb_kernel<<<dim3(256), 256, 0, stream>>>(Opart, Lpart, out);
}